// Round 5
// baseline (29.589 us; speedup 1.0000x reference)
//
#include <hip/hip_runtime.h>

#define ALPHA 0.2f
#define BATCH 16
#define WIN 100
#define KN 128          // nodes
#define DE 200          // embed dim
#define IT 8            // i-tile in k_attn_out

typedef float v2f __attribute__((ext_vector_type(2)));

// Kernel A: grid 16b x 25dt, 256 thr, ZERO LDS.
// wave -> (jh, dh): lane j = jh*64+lane, d-quad = dt*8 + dh*4.
// Weights/bias via uniform (s_load) path; x via coalesced VMEM.
//   Rt[b][d][j] = sum_w x[w][j]*lw[100+w][d] + lb[d]
//   Lt[b][d][j] = sum_w x[w][j]*lw[w][d]
__global__ __launch_bounds__(256) void k_lin(
    const float* __restrict__ in, const float* __restrict__ lw,
    const float* __restrict__ lb, float* __restrict__ Rt, float* __restrict__ Lt) {
  int blk = blockIdx.x;
  int b = blk / 25, dt = blk % 25;
  int t = threadIdx.x;
  int j = ((t >> 6) & 1) * 64 + (t & 63);
  int dbase = __builtin_amdgcn_readfirstlane(dt * 8 + (t >> 7) * 4);
  const float* inb = in + (size_t)b * WIN * KN + j;
  const float* lwl = lw + dbase;
  const float* lwr = lw + WIN * DE + dbase;
  float la0 = 0, la1 = 0, la2 = 0, la3 = 0;
  float ra0 = 0, ra1 = 0, ra2 = 0, ra3 = 0;
#pragma unroll 4
  for (int w = 0; w < WIN; ++w) {
    float x = inb[w * KN];
    float4 wl = *reinterpret_cast<const float4*>(lwl + w * DE);
    float4 wr = *reinterpret_cast<const float4*>(lwr + w * DE);
    la0 = fmaf(x, wl.x, la0); la1 = fmaf(x, wl.y, la1);
    la2 = fmaf(x, wl.z, la2); la3 = fmaf(x, wl.w, la3);
    ra0 = fmaf(x, wr.x, ra0); ra1 = fmaf(x, wr.y, ra1);
    ra2 = fmaf(x, wr.z, ra2); ra3 = fmaf(x, wr.w, ra3);
  }
  float4 bb = *reinterpret_cast<const float4*>(lb + dbase);
  float* rp = Rt + ((size_t)b * DE + dbase) * KN + j;
  float* lp = Lt + ((size_t)b * DE + dbase) * KN + j;
  rp[0 * KN] = ra0 + bb.x; rp[1 * KN] = ra1 + bb.y;
  rp[2 * KN] = ra2 + bb.z; rp[3 * KN] = ra3 + bb.w;
  lp[0 * KN] = la0; lp[1 * KN] = la1; lp[2 * KN] = la2; lp[3 * KN] = la3;
}

// Kernel B: per (b, 8-i tile), 512 thr.
//   M[ii][j]  = sum_d min(Lt[d][i0+ii]+Rt[d][j], 0) * aw[d]   (d split 4-way)
//   ra[j]     = sum_d Rt[d][j]*aw[d]
//   e[ii][j]  = ra[j] - 0.8*M[ii][j]   (shift-invariant form)
//   wave-per-row softmax; PV + sigmoid + store.
__global__ __launch_bounds__(512) void k_attn_out(
    const float* __restrict__ in, const float* __restrict__ aw,
    const float* __restrict__ Rt, const float* __restrict__ Lt,
    float* __restrict__ out) {
  int blk = blockIdx.x;
  int b = blk >> 4, it = blk & 15;
  int i0 = it * IT;
  int t = threadIdx.x;
  __shared__ float xs[WIN * 132];          // [w][j], stride 132 (16B-aligned rows)
  __shared__ float part[4][IT][KN];
  __shared__ float part_r[4][KN];
  __shared__ float ats[IT][132];

  const float* inb = in + (size_t)b * WIN * KN;
  // stage xs as float4
#pragma unroll
  for (int k = 0; k < 7; ++k) {
    int i4 = t + k * 512;
    if (i4 < WIN * KN / 4) {
      int w = i4 >> 5, jq = (i4 & 31) << 2;
      *reinterpret_cast<float4*>(&xs[w * 132 + jq]) =
          reinterpret_cast<const float4*>(inb)[i4];
    }
  }

  // e-phase (no LDS reads; Lt/aw via uniform s_load, Rt coalesced VMEM)
  {
    int j = t & (KN - 1);
    int dh = t >> 7;
    int db = __builtin_amdgcn_readfirstlane(dh * 50);
    const float* rtb = Rt + (size_t)b * DE * KN + j;
    const float* ltb = Lt + (size_t)b * DE * KN + i0;
    v2f acc0 = 0.f, acc1 = 0.f, acc2 = 0.f, acc3 = 0.f;
    float racc = 0.f;
#pragma unroll 2
    for (int dd = 0; dd < 50; ++dd) {
      int d = db + dd;
      float r = rtb[(size_t)d * KN];
      float a = aw[d];
      float4 L0 = *reinterpret_cast<const float4*>(ltb + (size_t)d * KN);
      float4 L1 = *reinterpret_cast<const float4*>(ltb + (size_t)d * KN + 4);
      racc = fmaf(r, a, racc);
      v2f rv = {r, r}, av = {a, a}, z = 0.f;
      v2f p0 = (v2f){L0.x, L0.y} + rv;
      v2f p1 = (v2f){L0.z, L0.w} + rv;
      v2f p2 = (v2f){L1.x, L1.y} + rv;
      v2f p3 = (v2f){L1.z, L1.w} + rv;
      p0 = __builtin_elementwise_min(p0, z);
      p1 = __builtin_elementwise_min(p1, z);
      p2 = __builtin_elementwise_min(p2, z);
      p3 = __builtin_elementwise_min(p3, z);
      acc0 += p0 * av; acc1 += p1 * av; acc2 += p2 * av; acc3 += p3 * av;
    }
    part[dh][0][j] = acc0.x; part[dh][1][j] = acc0.y;
    part[dh][2][j] = acc1.x; part[dh][3][j] = acc1.y;
    part[dh][4][j] = acc2.x; part[dh][5][j] = acc2.y;
    part[dh][6][j] = acc3.x; part[dh][7][j] = acc3.y;
    part_r[dh][j] = racc;
  }
  __syncthreads();

  // softmax: wave r (of 8) owns row r; 64 lanes x 2 j's
  {
    int r = t >> 6, l = t & 63;
    float ra0 = part_r[0][l] + part_r[1][l] + part_r[2][l] + part_r[3][l];
    float ra1 = part_r[0][l + 64] + part_r[1][l + 64] + part_r[2][l + 64] + part_r[3][l + 64];
    float m0 = part[0][r][l] + part[1][r][l] + part[2][r][l] + part[3][r][l];
    float m1 = part[0][r][l + 64] + part[1][r][l + 64] + part[2][r][l + 64] + part[3][r][l + 64];
    float e0 = fmaf(m0, -(1.f - ALPHA), ra0);
    float e1 = fmaf(m1, -(1.f - ALPHA), ra1);
    float m = fmaxf(e0, e1);
    for (int off = 32; off; off >>= 1) m = fmaxf(m, __shfl_xor(m, off));
    float p0 = __expf(e0 - m), p1 = __expf(e1 - m);
    float s = p0 + p1;
    for (int off = 32; off; off >>= 1) s += __shfl_xor(s, off);
    float inv = 1.f / s;
    ats[r][l] = p0 * inv;
    ats[r][l + 64] = p1 * inv;
  }
  __syncthreads();

  // PV: thread (w, q): out[b][w][i0 + q*2 + {0,1}]; float4 LDS reads
  if (t < 4 * WIN) {
    int w = t >> 2, q = t & 3;
    const float* xw = &xs[w * 132];
    const float* a0p = &ats[q * 2][0];
    const float* a1p = &ats[q * 2 + 1][0];
    float s0 = 0.f, s1 = 0.f;
#pragma unroll 8
    for (int j = 0; j < KN; j += 4) {
      float4 x4 = *reinterpret_cast<const float4*>(xw + j);
      float4 aa = *reinterpret_cast<const float4*>(a0p + j);
      float4 ab = *reinterpret_cast<const float4*>(a1p + j);
      s0 = fmaf(aa.x, x4.x, s0); s0 = fmaf(aa.y, x4.y, s0);
      s0 = fmaf(aa.z, x4.z, s0); s0 = fmaf(aa.w, x4.w, s0);
      s1 = fmaf(ab.x, x4.x, s1); s1 = fmaf(ab.y, x4.y, s1);
      s1 = fmaf(ab.z, x4.z, s1); s1 = fmaf(ab.w, x4.w, s1);
    }
    float o0 = 1.f / (1.f + __expf(-s0));
    float o1 = 1.f / (1.f + __expf(-s1));
    *reinterpret_cast<float2*>(&out[((size_t)b * WIN + w) * KN + i0 + q * 2]) =
        make_float2(o0, o1);
  }
}

extern "C" void kernel_launch(void* const* d_in, const int* in_sizes, int n_in,
                              void* d_out, int out_size, void* d_ws, size_t ws_size,
                              hipStream_t stream) {
  const float* in = (const float*)d_in[0];   // (16,100,128)
  const float* lw = (const float*)d_in[1];   // (200,200)
  const float* lb = (const float*)d_in[2];   // (200,)
  const float* aw = (const float*)d_in[3];   // (200,)
  float* out = (float*)d_out;                // (16,100,128)

  float* Rt = (float*)d_ws;                          // 16*200*128
  float* Lt = Rt + (size_t)BATCH * DE * KN;          // 16*200*128

  k_lin     <<<BATCH * 25, 256, 0, stream>>>(in, lw, lb, Rt, Lt);
  k_attn_out<<<BATCH * 16, 512, 0, stream>>>(in, aw, Rt, Lt, out);
}